// Round 2
// baseline (226.145 us; speedup 1.0000x reference)
//
#include <hip/hip_runtime.h>
#include <stdint.h>

typedef __attribute__((ext_vector_type(4))) float f32x4;
typedef __attribute__((ext_vector_type(8))) short s16x8;

__device__ __forceinline__ short f2bf(float f) {
    union { float f; uint32_t u; } v; v.f = f;
    uint32_t r = (v.u + 0x7FFFu + ((v.u >> 16) & 1u)) >> 16;
    return (short)(uint16_t)r;
}

// B=2 H=16 S=2048 D=64; fp32 in/out. scores*0.2, softmax (n=0), out*2.0
__global__ __launch_bounds__(256) void attn_fwd_kernel(
    const float* __restrict__ Q, const float* __restrict__ K,
    const float* __restrict__ V, float* __restrict__ O) {
  constexpr int S = 2048, D = 64;
  constexpr float SCALE = 0.2f, FACTOR = 2.0f;
  constexpr int KVBLK = 64, NT = S / KVBLK;

  __shared__ short kT[64 * 64];      // K tile [kv][d], XOR-swizzled rows
  __shared__ short vT[64 * 64];      // V tile transposed [d][kv], swizzled
  __shared__ short pT[4][16 * 64];   // per-wave P [q][kv], swizzled

  const int tid = threadIdx.x;
  const int w = tid >> 6;
  const int l = tid & 63;
  const int g = l >> 4;
  const int c = l & 15;

  const int bh = blockIdx.x >> 5;
  const int qt = blockIdx.x & 31;
  const size_t base = (size_t)bh * (size_t)(S * D);

  char* kB = (char*)kT;
  char* vB = (char*)vT;
  char* pB = (char*)pT[w];

  // ---- load Q fragments (kept in registers for the whole kernel) ----
  // A-frag: lane holds Q[row = l%16][k = (l/16)*8 + i] (+ kk*32)
  s16x8 qa[2];
  {
    const float* qp = Q + base + (size_t)(qt * 64 + w * 16 + c) * D + g * 8;
#pragma unroll
    for (int kk = 0; kk < 2; ++kk) {
      f32x4 q0 = *(const f32x4*)(qp + kk * 32);
      f32x4 q1 = *(const f32x4*)(qp + kk * 32 + 4);
      s16x8 a;
#pragma unroll
      for (int i = 0; i < 4; ++i) { a[i] = f2bf(q0[i]); a[4 + i] = f2bf(q1[i]); }
      qa[kk] = a;
    }
  }

  f32x4 o_acc[4];
#pragma unroll
  for (int nb = 0; nb < 4; ++nb) o_acc[nb] = (f32x4){0.f, 0.f, 0.f, 0.f};
  float m_r[4], l_r[4];
#pragma unroll
  for (int r = 0; r < 4; ++r) { m_r[r] = -1e30f; l_r[r] = 0.f; }

  // staging work split
  const int krow = tid >> 2;        // 0..63   (K: one row per 4 threads)
  const int kcb  = tid & 3;         // 16-col block
  const int vpr  = (tid >> 3) * 2;  // 0,2,..,62 (V: row pair)
  const int vpc  = (tid & 7) * 8;   // 0..56     (V: 8-col block)

  for (int kt = 0; kt < NT; ++kt) {
    const int kv0 = kt * KVBLK;
    __syncthreads();  // previous tile fully consumed

    // ---- stage K tile (row-major, swizzled) ----
    {
      const float* kp = K + base + (size_t)(kv0 + krow) * D + kcb * 16;
      f32x4 a0 = *(const f32x4*)(kp);
      f32x4 a1 = *(const f32x4*)(kp + 4);
      f32x4 a2 = *(const f32x4*)(kp + 8);
      f32x4 a3 = *(const f32x4*)(kp + 12);
      union { short s[8]; int4 v; } p0, p1;
#pragma unroll
      for (int i = 0; i < 4; ++i) {
        p0.s[i] = f2bf(a0[i]); p0.s[4 + i] = f2bf(a1[i]);
        p1.s[i] = f2bf(a2[i]); p1.s[4 + i] = f2bf(a3[i]);
      }
      const int sw = (krow & 7) << 4;
      *(int4*)(kB + krow * 128 + ((kcb * 32) ^ sw)) = p0.v;
      *(int4*)(kB + krow * 128 + ((kcb * 32 + 16) ^ sw)) = p1.v;
    }
    // ---- stage V tile transposed: vT[d][kv], packed b32 writes ----
    {
      const float* vp = V + base + (size_t)(kv0 + vpr) * D + vpc;
      f32x4 r0a = *(const f32x4*)(vp);
      f32x4 r0b = *(const f32x4*)(vp + 4);
      f32x4 r1a = *(const f32x4*)(vp + D);
      f32x4 r1b = *(const f32x4*)(vp + D + 4);
      float lo[8] = {r0a[0], r0a[1], r0a[2], r0a[3], r0b[0], r0b[1], r0b[2], r0b[3]};
      float hi[8] = {r1a[0], r1a[1], r1a[2], r1a[3], r1b[0], r1b[1], r1b[2], r1b[3]};
#pragma unroll
      for (int i = 0; i < 8; ++i) {
        uint32_t pk = (uint32_t)(uint16_t)f2bf(lo[i]) |
                      ((uint32_t)(uint16_t)f2bf(hi[i]) << 16);
        const int col = vpc + i;
        *(uint32_t*)(vB + col * 128 + ((vpr * 2) ^ ((col & 7) << 4))) = pk;
      }
    }
    __syncthreads();

    // ---- S = Q * K^T  (per wave: 16 q-rows x 64 kv) ----
    f32x4 sc[4];
#pragma unroll
    for (int nb = 0; nb < 4; ++nb) sc[nb] = (f32x4){0.f, 0.f, 0.f, 0.f};
#pragma unroll
    for (int kk = 0; kk < 2; ++kk) {
#pragma unroll
      for (int nb = 0; nb < 4; ++nb) {
        const int row = nb * 16 + c;
        s16x8 b = *(const s16x8*)(kB + row * 128 +
                                  ((kk * 64 + g * 16) ^ ((row & 7) << 4)));
        sc[nb] = __builtin_amdgcn_mfma_f32_16x16x32_bf16(qa[kk], b, sc[nb], 0, 0, 0);
      }
    }

    // ---- online softmax (C-layout: lane owns rows 4g+r, col c, per nb) ----
    float p[4][4];
    float esc[4];
#pragma unroll
    for (int r = 0; r < 4; ++r) {
      float mx = fmaxf(fmaxf(sc[0][r], sc[1][r]), fmaxf(sc[2][r], sc[3][r]));
#pragma unroll
      for (int mask = 1; mask < 16; mask <<= 1)
        mx = fmaxf(mx, __shfl_xor(mx, mask, 64));
      mx *= SCALE;
      const float mnew = fmaxf(m_r[r], mx);
      esc[r] = __expf(m_r[r] - mnew);
      float rs = 0.f;
#pragma unroll
      for (int nb = 0; nb < 4; ++nb) {
        float e = __expf(sc[nb][r] * SCALE - mnew);
        p[nb][r] = e;
        rs += e;
      }
#pragma unroll
      for (int mask = 1; mask < 16; mask <<= 1)
        rs += __shfl_xor(rs, mask, 64);
      l_r[r] = l_r[r] * esc[r] + rs;
      m_r[r] = mnew;
    }
#pragma unroll
    for (int nb = 0; nb < 4; ++nb)
#pragma unroll
      for (int r = 0; r < 4; ++r)
        o_acc[nb][r] *= esc[r];

    // ---- P -> per-wave LDS (C-layout -> A-layout transpose) ----
#pragma unroll
    for (int nb = 0; nb < 4; ++nb) {
#pragma unroll
      for (int r = 0; r < 4; ++r) {
        const int row = 4 * g + r;
        const int colb = (nb * 16 + c) * 2;
        *(short*)(pB + row * 128 + (colb ^ ((row & 7) << 4))) = f2bf(p[nb][r]);
      }
    }
    asm volatile("s_waitcnt lgkmcnt(0)" ::: "memory");  // same-wave cross-lane vis

    // ---- O += P * V ----
#pragma unroll
    for (int kk = 0; kk < 2; ++kk) {
      s16x8 pa = *(const s16x8*)(pB + c * 128 +
                                 ((kk * 64 + g * 16) ^ ((c & 7) << 4)));
#pragma unroll
      for (int nb = 0; nb < 4; ++nb) {
        const int row = nb * 16 + c;
        s16x8 vb = *(const s16x8*)(vB + row * 128 +
                                   ((kk * 64 + g * 16) ^ ((row & 7) << 4)));
        o_acc[nb] = __builtin_amdgcn_mfma_f32_16x16x32_bf16(pa, vb, o_acc[nb], 0, 0, 0);
      }
    }
  }

  // ---- epilogue: O = FACTOR * O_acc / l ----
#pragma unroll
  for (int r = 0; r < 4; ++r) {
    const float f = FACTOR / l_r[r];
    const size_t rowg = (size_t)(qt * 64 + w * 16 + 4 * g + r);
    float* op = O + base + rowg * D + c;
#pragma unroll
    for (int nb = 0; nb < 4; ++nb) op[nb * 16] = o_acc[nb][r] * f;
  }
}

extern "C" void kernel_launch(void* const* d_in, const int* in_sizes, int n_in,
                              void* d_out, int out_size, void* d_ws, size_t ws_size,
                              hipStream_t stream) {
  (void)in_sizes; (void)n_in; (void)d_ws; (void)ws_size; (void)out_size;
  const float* Q = (const float*)d_in[0];
  const float* K = (const float*)d_in[1];
  const float* V = (const float*)d_in[2];
  float* O = (float*)d_out;
  dim3 grid(1024), block(256);
  hipLaunchKernelGGL(attn_fwd_kernel, grid, block, 0, stream, Q, K, V, O);
}

// Round 3
// 201.508 us; speedup vs baseline: 1.1223x; 1.1223x over previous
//
#include <hip/hip_runtime.h>
#include <stdint.h>

typedef __attribute__((ext_vector_type(4))) float f32x4;
typedef __attribute__((ext_vector_type(8))) short s16x8;

__device__ __forceinline__ short f2bf(float f) {
    union { float f; uint32_t u; } v; v.f = f;
    uint32_t r = (v.u + 0x7FFFu + ((v.u >> 16) & 1u)) >> 16;
    return (short)(uint16_t)r;
}

__device__ __forceinline__ void async16(const short* g, short* lds) {
  __builtin_amdgcn_global_load_lds(
      (const __attribute__((address_space(1))) uint32_t*)g,
      (__attribute__((address_space(3))) uint32_t*)lds, 16, 0, 0);
}

// ---------------- pre-pass: K fp32 -> bf16 (layout unchanged) ----------------
__global__ __launch_bounds__(256) void conv_k_kernel(const float* __restrict__ K,
                                                     short* __restrict__ Kbf) {
  const int i = (blockIdx.x * 256 + threadIdx.x) * 8;
  f32x4 a = *(const f32x4*)(K + i);
  f32x4 b = *(const f32x4*)(K + i + 4);
  union { short s[8]; int4 v; } p;
#pragma unroll
  for (int j = 0; j < 4; ++j) { p.s[j] = f2bf(a[j]); p.s[4 + j] = f2bf(b[j]); }
  *(int4*)(Kbf + i) = p.v;
}

// ------------- pre-pass: V fp32 [bh][s][d] -> bf16 V^T [bh][d][s] -------------
__global__ __launch_bounds__(256) void conv_vt_kernel(const float* __restrict__ V,
                                                      short* __restrict__ VT) {
  __shared__ short t[64][72];  // padded: avoid bank conflicts on transpose read
  const int bh = blockIdx.x >> 5;
  const int st = blockIdx.x & 31;
  const size_t base = (size_t)bh * 131072;  // 2048*64
  {
    const int s_loc = threadIdx.x >> 2;
    const int dch = (threadIdx.x & 3) * 16;
    const float* p = V + base + (size_t)(st * 64 + s_loc) * 64 + dch;
#pragma unroll
    for (int j = 0; j < 16; j += 4) {
      f32x4 a = *(const f32x4*)(p + j);
#pragma unroll
      for (int q = 0; q < 4; ++q) t[s_loc][dch + j + q] = f2bf(a[q]);
    }
  }
  __syncthreads();
  {
    const int d_loc = threadIdx.x >> 2;
    const int sch = (threadIdx.x & 3) * 16;
    union { short s[16]; int4 v[2]; } o;
#pragma unroll
    for (int j = 0; j < 16; ++j) o.s[j] = t[sch + j][d_loc];
    short* out = VT + base + (size_t)d_loc * 2048 + st * 64 + sch;
    *(int4*)(out) = o.v[0];
    *(int4*)(out + 8) = o.v[1];
  }
}

// ---------------- main attention kernel (bf16 KV from workspace) -------------
// B=2 H=16 S=2048 D=64; scores*0.2, softmax(n=0), out*2.0
__global__ __launch_bounds__(256) void attn_fwd_v2(
    const float* __restrict__ Q, const short* __restrict__ Kbf,
    const short* __restrict__ VT, float* __restrict__ O) {
  constexpr int S = 2048, D = 64;
  constexpr float SCALE = 0.2f, FACTOR = 2.0f;
  constexpr int NT = S / 64;

  __shared__ short kT[2][4096];   // [kv][64d] bf16, chunk-swizzled
  __shared__ short vT[2][4096];   // [d][64kv] bf16, chunk-swizzled
  __shared__ short pT[4][1024];   // per-wave P [16q][64kv], swizzled

  const int tid = threadIdx.x;
  const int w = tid >> 6;
  const int l = tid & 63;
  const int g = l >> 4;
  const int c = l & 15;

  // XCD-chunked remap: each XCD (blocks with same id%8) owns 4 contiguous heads
  // -> its 4MB L2 holds those heads' bf16 KV (2MB). 1024 % 8 == 0 (bijective).
  const int rid = (blockIdx.x & 7) * 128 + (blockIdx.x >> 3);
  const int bh = rid >> 5;
  const int qt = rid & 31;
  const size_t base = (size_t)bh * (size_t)(S * D);

  const short* Kp = Kbf + base;
  const short* Vp = VT + base;
  char* pB = (char*)pT[w];

  // ---- Q fragments in registers: lane holds Q[l%16][ (l/16)*8 + i ] (+kk*32)
  s16x8 qa[2];
  {
    const float* qp = Q + base + (size_t)(qt * 64 + w * 16 + c) * D + g * 8;
#pragma unroll
    for (int kk = 0; kk < 2; ++kk) {
      f32x4 q0 = *(const f32x4*)(qp + kk * 32);
      f32x4 q1 = *(const f32x4*)(qp + kk * 32 + 4);
      s16x8 a;
#pragma unroll
      for (int i = 0; i < 4; ++i) { a[i] = f2bf(q0[i]); a[4 + i] = f2bf(q1[i]); }
      qa[kk] = a;
    }
  }

  // ---- staging maps: 2 x global_load_lds(16B) per wave per array per tile.
  // LDS dest linear chunk t = i*256 + w*64 + l; row = t>>3, ch = t&7.
  // Source chunk pre-swizzled: ch_g = ch ^ (row&7)  (involution; read XORs back)
  int kOff[2], vOff[2], ldsT[2];
#pragma unroll
  for (int i = 0; i < 2; ++i) {
    const int t = i * 256 + w * 64 + l;
    const int row = t >> 3, ch = t & 7;
    ldsT[i] = t * 8;                            // short index (16B per chunk)
    kOff[i] = row * 64 + ((ch ^ (row & 7)) << 3);    // K row-major [kv][64]
    vOff[i] = row * 2048 + ((ch ^ (row & 7)) << 3);  // V^T [d][2048]
  }
#define STAGE(buf, kv0s)                                        \
  do {                                                          \
    _Pragma("unroll") for (int i = 0; i < 2; ++i) {             \
      async16(Kp + (kv0s) * 64 + kOff[i], &kT[buf][ldsT[i]]);   \
      async16(Vp + (kv0s) + vOff[i], &vT[buf][ldsT[i]]);        \
    }                                                           \
  } while (0)

  f32x4 o_acc[4];
#pragma unroll
  for (int nb = 0; nb < 4; ++nb) o_acc[nb] = (f32x4){0.f, 0.f, 0.f, 0.f};
  float m_r[4], l_r[4];
#pragma unroll
  for (int r = 0; r < 4; ++r) { m_r[r] = -1e30f; l_r[r] = 0.f; }

  int cur = 0;
  STAGE(0, 0);
  for (int kt = 0; kt < NT; ++kt) {
    __syncthreads();  // drains vmcnt: buf[cur] ready; buf[cur^1] reads done
    if (kt + 1 < NT) STAGE(cur ^ 1, (kt + 1) * 64);

    const char* kB = (const char*)kT[cur];
    const char* vB = (const char*)vT[cur];

    // ---- S = Q * K^T (per wave: 16 q-rows x 64 kv) ----
    f32x4 sc[4];
#pragma unroll
    for (int nb = 0; nb < 4; ++nb) sc[nb] = (f32x4){0.f, 0.f, 0.f, 0.f};
#pragma unroll
    for (int kk = 0; kk < 2; ++kk) {
#pragma unroll
      for (int nb = 0; nb < 4; ++nb) {
        const int row = nb * 16 + c;
        s16x8 b = *(const s16x8*)(kB + row * 128 +
                                  ((kk * 64 + g * 16) ^ ((row & 7) << 4)));
        sc[nb] = __builtin_amdgcn_mfma_f32_16x16x32_bf16(qa[kk], b, sc[nb], 0, 0, 0);
      }
    }

    // ---- online softmax (C-layout: lane owns rows 4g+r, col c, per nb) ----
    float p[4][4];
    float esc[4];
#pragma unroll
    for (int r = 0; r < 4; ++r) {
      float mx = fmaxf(fmaxf(sc[0][r], sc[1][r]), fmaxf(sc[2][r], sc[3][r]));
#pragma unroll
      for (int mask = 1; mask < 16; mask <<= 1)
        mx = fmaxf(mx, __shfl_xor(mx, mask, 64));
      mx *= SCALE;
      const float mnew = fmaxf(m_r[r], mx);
      esc[r] = __expf(m_r[r] - mnew);
      float rs = 0.f;
#pragma unroll
      for (int nb = 0; nb < 4; ++nb) {
        float e = __expf(sc[nb][r] * SCALE - mnew);
        p[nb][r] = e;
        rs += e;
      }
#pragma unroll
      for (int mask = 1; mask < 16; mask <<= 1)
        rs += __shfl_xor(rs, mask, 64);
      l_r[r] = l_r[r] * esc[r] + rs;
      m_r[r] = mnew;
    }
#pragma unroll
    for (int nb = 0; nb < 4; ++nb)
#pragma unroll
      for (int r = 0; r < 4; ++r)
        o_acc[nb][r] *= esc[r];

    // ---- P -> per-wave LDS (C-layout -> A-layout transpose) ----
#pragma unroll
    for (int nb = 0; nb < 4; ++nb) {
#pragma unroll
      for (int r = 0; r < 4; ++r) {
        const int row = 4 * g + r;
        const int colb = (nb * 16 + c) * 2;
        *(short*)(pB + row * 128 + (colb ^ ((row & 7) << 4))) = f2bf(p[nb][r]);
      }
    }
    asm volatile("s_waitcnt lgkmcnt(0)" ::: "memory");  // same-wave cross-lane vis

    // ---- O += P * V ----
#pragma unroll
    for (int kk = 0; kk < 2; ++kk) {
      s16x8 pa = *(const s16x8*)(pB + c * 128 +
                                 ((kk * 64 + g * 16) ^ ((c & 7) << 4)));
#pragma unroll
      for (int nb = 0; nb < 4; ++nb) {
        const int row = nb * 16 + c;
        s16x8 vb = *(const s16x8*)(vB + row * 128 +
                                   ((kk * 64 + g * 16) ^ ((row & 7) << 4)));
        o_acc[nb] = __builtin_amdgcn_mfma_f32_16x16x32_bf16(pa, vb, o_acc[nb], 0, 0, 0);
      }
    }
    cur ^= 1;
  }
#undef STAGE

  // ---- epilogue: O = FACTOR * O_acc / l ----
#pragma unroll
  for (int r = 0; r < 4; ++r) {
    const float f = FACTOR / l_r[r];
    const size_t rowg = (size_t)(qt * 64 + w * 16 + 4 * g + r);
    float* op = O + base + rowg * D + c;
#pragma unroll
    for (int nb = 0; nb < 4; ++nb) op[nb * 16] = o_acc[nb][r] * f;
  }
}

// ================= fallback (round-0 kernel, no workspace) ===================
__global__ __launch_bounds__(256) void attn_fwd_v1(
    const float* __restrict__ Q, const float* __restrict__ K,
    const float* __restrict__ V, float* __restrict__ O) {
  constexpr int S = 2048, D = 64;
  constexpr float SCALE = 0.2f, FACTOR = 2.0f;
  constexpr int KVBLK = 64, NT = S / KVBLK;
  __shared__ short kT[64 * 64];
  __shared__ short vT[64 * 64];
  __shared__ short pT[4][16 * 64];
  const int tid = threadIdx.x;
  const int w = tid >> 6, l = tid & 63, g = l >> 4, c = l & 15;
  const int bh = blockIdx.x >> 5, qt = blockIdx.x & 31;
  const size_t base = (size_t)bh * (size_t)(S * D);
  char* kB = (char*)kT; char* vB = (char*)vT; char* pB = (char*)pT[w];
  s16x8 qa[2];
  {
    const float* qp = Q + base + (size_t)(qt * 64 + w * 16 + c) * D + g * 8;
#pragma unroll
    for (int kk = 0; kk < 2; ++kk) {
      f32x4 q0 = *(const f32x4*)(qp + kk * 32);
      f32x4 q1 = *(const f32x4*)(qp + kk * 32 + 4);
      s16x8 a;
#pragma unroll
      for (int i = 0; i < 4; ++i) { a[i] = f2bf(q0[i]); a[4 + i] = f2bf(q1[i]); }
      qa[kk] = a;
    }
  }
  f32x4 o_acc[4];
#pragma unroll
  for (int nb = 0; nb < 4; ++nb) o_acc[nb] = (f32x4){0.f, 0.f, 0.f, 0.f};
  float m_r[4], l_r[4];
#pragma unroll
  for (int r = 0; r < 4; ++r) { m_r[r] = -1e30f; l_r[r] = 0.f; }
  const int krow = tid >> 2, kcb = tid & 3;
  const int vpr = (tid >> 3) * 2, vpc = (tid & 7) * 8;
  for (int kt = 0; kt < NT; ++kt) {
    const int kv0 = kt * KVBLK;
    __syncthreads();
    {
      const float* kp = K + base + (size_t)(kv0 + krow) * D + kcb * 16;
      f32x4 a0 = *(const f32x4*)(kp);
      f32x4 a1 = *(const f32x4*)(kp + 4);
      f32x4 a2 = *(const f32x4*)(kp + 8);
      f32x4 a3 = *(const f32x4*)(kp + 12);
      union { short s[8]; int4 v; } p0, p1;
#pragma unroll
      for (int i = 0; i < 4; ++i) {
        p0.s[i] = f2bf(a0[i]); p0.s[4 + i] = f2bf(a1[i]);
        p1.s[i] = f2bf(a2[i]); p1.s[4 + i] = f2bf(a3[i]);
      }
      const int sw = (krow & 7) << 4;
      *(int4*)(kB + krow * 128 + ((kcb * 32) ^ sw)) = p0.v;
      *(int4*)(kB + krow * 128 + ((kcb * 32 + 16) ^ sw)) = p1.v;
    }
    {
      const float* vp = V + base + (size_t)(kv0 + vpr) * D + vpc;
      f32x4 r0a = *(const f32x4*)(vp);
      f32x4 r0b = *(const f32x4*)(vp + 4);
      f32x4 r1a = *(const f32x4*)(vp + D);
      f32x4 r1b = *(const f32x4*)(vp + D + 4);
      float lo[8] = {r0a[0], r0a[1], r0a[2], r0a[3], r0b[0], r0b[1], r0b[2], r0b[3]};
      float hi[8] = {r1a[0], r1a[1], r1a[2], r1a[3], r1b[0], r1b[1], r1b[2], r1b[3]};
#pragma unroll
      for (int i = 0; i < 8; ++i) {
        uint32_t pk = (uint32_t)(uint16_t)f2bf(lo[i]) |
                      ((uint32_t)(uint16_t)f2bf(hi[i]) << 16);
        const int col = vpc + i;
        *(uint32_t*)(vB + col * 128 + ((vpr * 2) ^ ((col & 7) << 4))) = pk;
      }
    }
    __syncthreads();
    f32x4 sc[4];
#pragma unroll
    for (int nb = 0; nb < 4; ++nb) sc[nb] = (f32x4){0.f, 0.f, 0.f, 0.f};
#pragma unroll
    for (int kk = 0; kk < 2; ++kk) {
#pragma unroll
      for (int nb = 0; nb < 4; ++nb) {
        const int row = nb * 16 + c;
        s16x8 b = *(const s16x8*)(kB + row * 128 +
                                  ((kk * 64 + g * 16) ^ ((row & 7) << 4)));
        sc[nb] = __builtin_amdgcn_mfma_f32_16x16x32_bf16(qa[kk], b, sc[nb], 0, 0, 0);
      }
    }
    float p[4][4]; float esc[4];
#pragma unroll
    for (int r = 0; r < 4; ++r) {
      float mx = fmaxf(fmaxf(sc[0][r], sc[1][r]), fmaxf(sc[2][r], sc[3][r]));
#pragma unroll
      for (int mask = 1; mask < 16; mask <<= 1)
        mx = fmaxf(mx, __shfl_xor(mx, mask, 64));
      mx *= SCALE;
      const float mnew = fmaxf(m_r[r], mx);
      esc[r] = __expf(m_r[r] - mnew);
      float rs = 0.f;
#pragma unroll
      for (int nb = 0; nb < 4; ++nb) {
        float e = __expf(sc[nb][r] * SCALE - mnew);
        p[nb][r] = e; rs += e;
      }
#pragma unroll
      for (int mask = 1; mask < 16; mask <<= 1)
        rs += __shfl_xor(rs, mask, 64);
      l_r[r] = l_r[r] * esc[r] + rs;
      m_r[r] = mnew;
    }
#pragma unroll
    for (int nb = 0; nb < 4; ++nb)
#pragma unroll
      for (int r = 0; r < 4; ++r) o_acc[nb][r] *= esc[r];
#pragma unroll
    for (int nb = 0; nb < 4; ++nb) {
#pragma unroll
      for (int r = 0; r < 4; ++r) {
        const int row = 4 * g + r;
        const int colb = (nb * 16 + c) * 2;
        *(short*)(pB + row * 128 + (colb ^ ((row & 7) << 4))) = f2bf(p[nb][r]);
      }
    }
    asm volatile("s_waitcnt lgkmcnt(0)" ::: "memory");
#pragma unroll
    for (int kk = 0; kk < 2; ++kk) {
      s16x8 pa = *(const s16x8*)(pB + c * 128 +
                                 ((kk * 64 + g * 16) ^ ((c & 7) << 4)));
#pragma unroll
      for (int nb = 0; nb < 4; ++nb) {
        const int row = nb * 16 + c;
        s16x8 vb = *(const s16x8*)(vB + row * 128 +
                                   ((kk * 64 + g * 16) ^ ((row & 7) << 4)));
        o_acc[nb] = __builtin_amdgcn_mfma_f32_16x16x32_bf16(pa, vb, o_acc[nb], 0, 0, 0);
      }
    }
  }
#pragma unroll
  for (int r = 0; r < 4; ++r) {
    const float f = FACTOR / l_r[r];
    const size_t rowg = (size_t)(qt * 64 + w * 16 + 4 * g + r);
    float* op = O + base + rowg * D + c;
#pragma unroll
    for (int nb = 0; nb < 4; ++nb) op[nb * 16] = o_acc[nb][r] * f;
  }
}

extern "C" void kernel_launch(void* const* d_in, const int* in_sizes, int n_in,
                              void* d_out, int out_size, void* d_ws, size_t ws_size,
                              hipStream_t stream) {
  (void)in_sizes; (void)n_in; (void)out_size;
  const float* Q = (const float*)d_in[0];
  const float* K = (const float*)d_in[1];
  const float* V = (const float*)d_in[2];
  float* O = (float*)d_out;
  constexpr size_t NEED = 2ull * 2 * 16 * 2048 * 64 * sizeof(short);  // 16.78 MB
  if (ws_size >= NEED && d_ws) {
    short* Kbf = (short*)d_ws;
    short* VT = Kbf + 2 * 16 * 2048 * 64;
    hipLaunchKernelGGL(conv_k_kernel, dim3(2048), dim3(256), 0, stream, K, Kbf);
    hipLaunchKernelGGL(conv_vt_kernel, dim3(1024), dim3(256), 0, stream, V, VT);
    hipLaunchKernelGGL(attn_fwd_v2, dim3(1024), dim3(256), 0, stream, Q, Kbf, VT, O);
  } else {
    hipLaunchKernelGGL(attn_fwd_v1, dim3(1024), dim3(256), 0, stream, Q, K, V, O);
  }
}

// Round 5
// 169.522 us; speedup vs baseline: 1.3340x; 1.1887x over previous
//
#include <hip/hip_runtime.h>
#include <hip/hip_bf16.h>
#include <stdint.h>

typedef __attribute__((ext_vector_type(4))) float f32x4;
typedef __attribute__((ext_vector_type(16))) float f32x16;
typedef __attribute__((ext_vector_type(8))) short s16x8;

__device__ __forceinline__ short f2bf(float f) {
    union { float f; uint32_t u; } v; v.f = f;
    uint32_t r = (v.u + 0x7FFFu + ((v.u >> 16) & 1u)) >> 16;
    return (short)(uint16_t)r;
}

__device__ __forceinline__ uint32_t pk2(float a, float b) {
  union { __hip_bfloat162 h; uint32_t u; } v;
  v.h = __float22bfloat162_rn(make_float2(a, b));
  return v.u;
}

__device__ __forceinline__ void async16(const short* g, short* lds) {
  __builtin_amdgcn_global_load_lds(
      (const __attribute__((address_space(1))) uint32_t*)g,
      (__attribute__((address_space(3))) uint32_t*)lds, 16, 0, 0);
}

// ---- fused pre-pass: K fp32->bf16 (same layout) + V fp32 -> permuted V^T ----
// V^T slot order within each 16-kv group: [q0 q2 q1 q3] quads (even quads first)
// so PV B-fragments need no cross-lane exchange (sigma trick).
__global__ __launch_bounds__(256) void conv_kv_kernel(
    const float* __restrict__ K, const float* __restrict__ V,
    short* __restrict__ Kbf, short* __restrict__ VT) {
  __shared__ short t[64][72];  // padded transpose buffer
  const int bh = blockIdx.x >> 5;
  const int st = blockIdx.x & 31;
  const size_t base = (size_t)bh * 131072;  // 2048*64

  // --- part A: K convert (row-major passthrough) ---
  {
    const int row = threadIdx.x >> 2;
    const int cb = (threadIdx.x & 3) * 16;
    const float* kp = K + base + (size_t)(st * 64 + row) * 64 + cb;
    union { short s[16]; int4 v[2]; } o;
#pragma unroll
    for (int j = 0; j < 16; j += 4) {
      f32x4 a = *(const f32x4*)(kp + j);
#pragma unroll
      for (int q = 0; q < 4; ++q) o.s[j + q] = f2bf(a[q]);
    }
    short* out = Kbf + base + (size_t)(st * 64 + row) * 64 + cb;
    *(int4*)(out) = o.v[0];
    *(int4*)(out + 8) = o.v[1];
  }

  // --- part B: V transpose + quad-permute ---
  {
    const int s_loc = threadIdx.x >> 2;
    const int dch = (threadIdx.x & 3) * 16;
    const float* p = V + base + (size_t)(st * 64 + s_loc) * 64 + dch;
#pragma unroll
    for (int j = 0; j < 16; j += 4) {
      f32x4 a = *(const f32x4*)(p + j);
#pragma unroll
      for (int q = 0; q < 4; ++q) t[s_loc][dch + j + q] = f2bf(a[q]);
    }
  }
  __syncthreads();
  {
    const int d_loc = threadIdx.x >> 2;
    const int sch = (threadIdx.x & 3) * 16;
    union { short s[16]; int4 v[2]; } o;
    // slot i holds kv j where (i: 0-3<-j0-3, 4-7<-j8-11, 8-11<-j4-7, 12-15<-j12-15)
#pragma unroll
    for (int i = 0; i < 4; ++i) {
      o.s[i]      = t[sch + i][d_loc];
      o.s[4 + i]  = t[sch + 8 + i][d_loc];
      o.s[8 + i]  = t[sch + 4 + i][d_loc];
      o.s[12 + i] = t[sch + 12 + i][d_loc];
    }
    short* out = VT + base + (size_t)d_loc * 2048 + st * 64 + sch;
    *(int4*)(out) = o.v[0];
    *(int4*)(out + 8) = o.v[1];
  }
}

// --------------- main kernel: swapped-QK^T 32x32 structure -------------------
// Per warp: 32 q-rows (q = lane&31). Scores via mfma(K,Q): lane holds
// S[kv in 16 regs][q] — softmax nearly all in-register; P stays in registers
// and feeds PV directly thanks to the sigma-permuted V^T layout.
__global__ __launch_bounds__(256) void attn_fwd_v3(
    const float* __restrict__ Q, const short* __restrict__ Kbf,
    const short* __restrict__ VT, float* __restrict__ O) {
  constexpr int S = 2048, D = 64;
  constexpr int NT = S / 64;
  constexpr float K1 = 0.28853901f;   // SCALE * log2(e)
  constexpr float THR = 11.5415603f;  // 8 nats in log2 units

  __shared__ short kT[2][4096];  // [kv 64][d 64] bf16, chunk-swizzled
  __shared__ short vS[2][4096];  // [d 64][kv' 64] bf16 (sigma order), swizzled

  const int tid = threadIdx.x;
  const int w = tid >> 6;    // warp 0..3
  const int l = tid & 63;
  const int hi = l >> 5;
  const int c32 = l & 31;

  // XCD-chunked remap (512 % 8 == 0, bijective): each XCD owns 4 heads' KV.
  const int rid = (blockIdx.x & 7) * 64 + (blockIdx.x >> 3);
  const int bh = rid >> 4;
  const int qt = rid & 15;
  const size_t base = (size_t)bh * (size_t)(S * D);
  const int qrow = qt * 128 + w * 32 + c32;

  const short* Kp = Kbf + base;
  const short* Vp = VT + base;

  // ---- Q fragments (pre-scaled by SCALE*log2e): B-frag for mfma(K,Q).
  // qreg[j] element i = Q[qrow][j*16 + hi*8 + i]
  s16x8 qreg[4];
  {
    const float* qp = Q + base + (size_t)qrow * D;
#pragma unroll
    for (int j = 0; j < 4; ++j) {
      f32x4 a = *(const f32x4*)(qp + j * 16 + hi * 8);
      f32x4 b = *(const f32x4*)(qp + j * 16 + hi * 8 + 4);
      union { uint32_t u[4]; s16x8 v; } pk;
      pk.u[0] = pk2(a[0] * K1, a[1] * K1);
      pk.u[1] = pk2(a[2] * K1, a[3] * K1);
      pk.u[2] = pk2(b[0] * K1, b[1] * K1);
      pk.u[3] = pk2(b[2] * K1, b[3] * K1);
      qreg[j] = pk.v;
    }
  }

  // ---- staging offsets: 2 x 16B chunks per array per thread (512 total) ----
  int kSrc[2], vSrc[2], ldsOff[2];
#pragma unroll
  for (int i = 0; i < 2; ++i) {
    const int t = i * 256 + tid;
    const int row = t >> 3, ch = t & 7;
    ldsOff[i] = t * 8;
    kSrc[i] = row * 64 + ((ch ^ (row & 7)) << 3);    // K [kv][64]
    vSrc[i] = row * 2048 + ((ch ^ (row & 7)) << 3);  // V^T [d][2048]
  }
#define STAGE(buf, kv0)                                       \
  do {                                                        \
    _Pragma("unroll") for (int i = 0; i < 2; ++i) {           \
      async16(Kp + (kv0) * 64 + kSrc[i], &kT[buf][ldsOff[i]]); \
      async16(Vp + (kv0) + vSrc[i], &vS[buf][ldsOff[i]]);      \
    }                                                         \
  } while (0)

  f32x16 o0, o1;
#pragma unroll
  for (int i = 0; i < 16; ++i) { o0[i] = 0.f; o1[i] = 0.f; }
  float m = -1e30f, lsum = 0.f;

  int cur = 0;
  STAGE(0, 0);
  for (int kt = 0; kt < NT; ++kt) {
    __syncthreads();  // vmcnt(0) drained by compiler before barrier
    if (kt + 1 < NT) STAGE(cur ^ 1, (kt + 1) * 64);
    const char* kB = (const char*)kT[cur];
    const char* vB = (const char*)vS[cur];

#pragma unroll
    for (int grp = 0; grp < 2; ++grp) {
      // ---- scores: S^T[kv][q] = K * Q^T, kv-rows = grp*32 + C-layout rows ----
      f32x16 s;
#pragma unroll
      for (int i = 0; i < 16; ++i) s[i] = 0.f;
      const int krow = grp * 32 + c32;
      const int ksw = (krow & 7) << 4;
      __builtin_amdgcn_s_setprio(1);
#pragma unroll
      for (int j = 0; j < 4; ++j) {
        s16x8 a = *(const s16x8*)(kB + krow * 128 + ((j * 32 + hi * 16) ^ ksw));
        s = __builtin_amdgcn_mfma_f32_32x32x16_bf16(a, qreg[j], s, 0, 0, 0);
      }
      __builtin_amdgcn_s_setprio(0);

      // ---- online softmax (base-2 units; q = c32 fixed per lane) ----
      float t8[8];
#pragma unroll
      for (int i = 0; i < 8; ++i) t8[i] = fmaxf(s[2 * i], s[2 * i + 1]);
      float t4a = fmaxf(fmaxf(t8[0], t8[1]), fmaxf(t8[2], t8[3]));
      float t4b = fmaxf(fmaxf(t8[4], t8[5]), fmaxf(t8[6], t8[7]));
      float tm = fmaxf(t4a, t4b);
      tm = fmaxf(tm, __shfl_xor(tm, 32));
      if (!__all(tm <= m + THR)) {  // defer-max (T13)
        const float mn = fmaxf(m, tm);
        const float scl = exp2f(m - mn);
        lsum *= scl;
        o0 *= scl;
        o1 *= scl;
        m = mn;
      }
      float p[16];
#pragma unroll
      for (int i = 0; i < 16; ++i) p[i] = exp2f(s[i] - m);
      float s8[8];
#pragma unroll
      for (int i = 0; i < 8; ++i) s8[i] = p[2 * i] + p[2 * i + 1];
      float rsa = (s8[0] + s8[1]) + (s8[2] + s8[3]);
      float rsb = (s8[4] + s8[5]) + (s8[6] + s8[7]);
      float rs = rsa + rsb;
      rs += __shfl_xor(rs, 32);
      lsum += rs;

      // ---- pack P to bf16 B-fragments (register-only; sigma order) ----
      union { uint32_t u[8]; s16x8 v[2]; } wp;
#pragma unroll
      for (int i = 0; i < 8; ++i) wp.u[i] = pk2(p[2 * i], p[2 * i + 1]);

      // ---- O^T += V^T * P ----
      __builtin_amdgcn_s_setprio(1);
#pragma unroll
      for (int c = 0; c < 2; ++c) {
        const s16x8 bp = wp.v[c];
        {
          const int vrow = c32;  // dblk 0
          s16x8 av = *(const s16x8*)(vB + vrow * 128 +
                                     ((grp * 64 + c * 32 + hi * 16) ^ ((vrow & 7) << 4)));
          o0 = __builtin_amdgcn_mfma_f32_32x32x16_bf16(av, bp, o0, 0, 0, 0);
        }
        {
          const int vrow = 32 + c32;  // dblk 1
          s16x8 av = *(const s16x8*)(vB + vrow * 128 +
                                     ((grp * 64 + c * 32 + hi * 16) ^ ((vrow & 7) << 4)));
          o1 = __builtin_amdgcn_mfma_f32_32x32x16_bf16(av, bp, o1, 0, 0, 0);
        }
      }
      __builtin_amdgcn_s_setprio(0);
    }
    cur ^= 1;
  }
#undef STAGE

  // ---- epilogue: O[q][d] = FACTOR * O^T / lsum ----
  const float f = 2.0f / lsum;
  float* op = O + base + (size_t)qrow * D;
#pragma unroll
  for (int rq = 0; rq < 4; ++rq) {
    const int d0 = rq * 8 + 4 * hi;
    f32x4 v0, v1;
#pragma unroll
    for (int i = 0; i < 4; ++i) {
      v0[i] = o0[rq * 4 + i] * f;
      v1[i] = o1[rq * 4 + i] * f;
    }
    *(f32x4*)(op + d0) = v0;
    *(f32x4*)(op + d0 + 32) = v1;
  }
}

// ================= fallback (round-0 kernel, no workspace) ===================
__global__ __launch_bounds__(256) void attn_fwd_v1(
    const float* __restrict__ Q, const float* __restrict__ K,
    const float* __restrict__ V, float* __restrict__ O) {
  constexpr int S = 2048, D = 64;
  constexpr float SCALE = 0.2f, FACTOR = 2.0f;
  constexpr int KVBLK = 64, NT = S / KVBLK;
  __shared__ short kT[64 * 64];
  __shared__ short vT[64 * 64];
  __shared__ short pT[4][16 * 64];
  const int tid = threadIdx.x;
  const int w = tid >> 6, l = tid & 63, g = l >> 4, c = l & 15;
  const int bh = blockIdx.x >> 5, qt = blockIdx.x & 31;
  const size_t base = (size_t)bh * (size_t)(S * D);
  char* kB = (char*)kT; char* vB = (char*)vT; char* pB = (char*)pT[w];
  s16x8 qa[2];
  {
    const float* qp = Q + base + (size_t)(qt * 64 + w * 16 + c) * D + g * 8;
#pragma unroll
    for (int kk = 0; kk < 2; ++kk) {
      f32x4 q0 = *(const f32x4*)(qp + kk * 32);
      f32x4 q1 = *(const f32x4*)(qp + kk * 32 + 4);
      s16x8 a;
#pragma unroll
      for (int i = 0; i < 4; ++i) { a[i] = f2bf(q0[i]); a[4 + i] = f2bf(q1[i]); }
      qa[kk] = a;
    }
  }
  f32x4 o_acc[4];
#pragma unroll
  for (int nb = 0; nb < 4; ++nb) o_acc[nb] = (f32x4){0.f, 0.f, 0.f, 0.f};
  float m_r[4], l_r[4];
#pragma unroll
  for (int r = 0; r < 4; ++r) { m_r[r] = -1e30f; l_r[r] = 0.f; }
  const int krow = tid >> 2, kcb = tid & 3;
  const int vpr = (tid >> 3) * 2, vpc = (tid & 7) * 8;
  for (int kt = 0; kt < NT; ++kt) {
    const int kv0 = kt * KVBLK;
    __syncthreads();
    {
      const float* kp = K + base + (size_t)(kv0 + krow) * D + kcb * 16;
      f32x4 a0 = *(const f32x4*)(kp);
      f32x4 a1 = *(const f32x4*)(kp + 4);
      f32x4 a2 = *(const f32x4*)(kp + 8);
      f32x4 a3 = *(const f32x4*)(kp + 12);
      union { short s[8]; int4 v; } p0, p1;
#pragma unroll
      for (int i = 0; i < 4; ++i) {
        p0.s[i] = f2bf(a0[i]); p0.s[4 + i] = f2bf(a1[i]);
        p1.s[i] = f2bf(a2[i]); p1.s[4 + i] = f2bf(a3[i]);
      }
      const int sw = (krow & 7) << 4;
      *(int4*)(kB + krow * 128 + ((kcb * 32) ^ sw)) = p0.v;
      *(int4*)(kB + krow * 128 + ((kcb * 32 + 16) ^ sw)) = p1.v;
    }
    {
      const float* vp = V + base + (size_t)(kv0 + vpr) * D + vpc;
      f32x4 r0a = *(const f32x4*)(vp);
      f32x4 r0b = *(const f32x4*)(vp + 4);
      f32x4 r1a = *(const f32x4*)(vp + D);
      f32x4 r1b = *(const f32x4*)(vp + D + 4);
      float lo[8] = {r0a[0], r0a[1], r0a[2], r0a[3], r0b[0], r0b[1], r0b[2], r0b[3]};
      float hi2[8] = {r1a[0], r1a[1], r1a[2], r1a[3], r1b[0], r1b[1], r1b[2], r1b[3]};
#pragma unroll
      for (int i = 0; i < 8; ++i) {
        uint32_t pk = (uint32_t)(uint16_t)f2bf(lo[i]) |
                      ((uint32_t)(uint16_t)f2bf(hi2[i]) << 16);
        const int col = vpc + i;
        *(uint32_t*)(vB + col * 128 + ((vpr * 2) ^ ((col & 7) << 4))) = pk;
      }
    }
    __syncthreads();
    f32x4 sc[4];
#pragma unroll
    for (int nb = 0; nb < 4; ++nb) sc[nb] = (f32x4){0.f, 0.f, 0.f, 0.f};
#pragma unroll
    for (int kk = 0; kk < 2; ++kk) {
#pragma unroll
      for (int nb = 0; nb < 4; ++nb) {
        const int row = nb * 16 + c;
        s16x8 b = *(const s16x8*)(kB + row * 128 +
                                  ((kk * 64 + g * 16) ^ ((row & 7) << 4)));
        sc[nb] = __builtin_amdgcn_mfma_f32_16x16x32_bf16(qa[kk], b, sc[nb], 0, 0, 0);
      }
    }
    float p[4][4]; float esc[4];
#pragma unroll
    for (int r = 0; r < 4; ++r) {
      float mx = fmaxf(fmaxf(sc[0][r], sc[1][r]), fmaxf(sc[2][r], sc[3][r]));
#pragma unroll
      for (int mask = 1; mask < 16; mask <<= 1)
        mx = fmaxf(mx, __shfl_xor(mx, mask, 64));
      mx *= SCALE;
      const float mnew = fmaxf(m_r[r], mx);
      esc[r] = __expf(m_r[r] - mnew);
      float rs = 0.f;
#pragma unroll
      for (int nb = 0; nb < 4; ++nb) {
        float e = __expf(sc[nb][r] * SCALE - mnew);
        p[nb][r] = e; rs += e;
      }
#pragma unroll
      for (int mask = 1; mask < 16; mask <<= 1)
        rs += __shfl_xor(rs, mask, 64);
      l_r[r] = l_r[r] * esc[r] + rs;
      m_r[r] = mnew;
    }
#pragma unroll
    for (int nb = 0; nb < 4; ++nb)
#pragma unroll
      for (int r = 0; r < 4; ++r) o_acc[nb][r] *= esc[r];
#pragma unroll
    for (int nb = 0; nb < 4; ++nb) {
#pragma unroll
      for (int r = 0; r < 4; ++r) {
        const int row = 4 * g + r;
        const int colb = (nb * 16 + c) * 2;
        *(short*)(pB + row * 128 + (colb ^ ((row & 7) << 4))) = f2bf(p[nb][r]);
      }
    }
    asm volatile("s_waitcnt lgkmcnt(0)" ::: "memory");
#pragma unroll
    for (int kk = 0; kk < 2; ++kk) {
      s16x8 pa = *(const s16x8*)(pB + c * 128 +
                                 ((kk * 64 + g * 16) ^ ((c & 7) << 4)));
#pragma unroll
      for (int nb = 0; nb < 4; ++nb) {
        const int row = nb * 16 + c;
        s16x8 vb = *(const s16x8*)(vB + row * 128 +
                                   ((kk * 64 + g * 16) ^ ((row & 7) << 4)));
        o_acc[nb] = __builtin_amdgcn_mfma_f32_16x16x32_bf16(pa, vb, o_acc[nb], 0, 0, 0);
      }
    }
  }
#pragma unroll
  for (int r = 0; r < 4; ++r) {
    const float f = FACTOR / l_r[r];
    const size_t rowg = (size_t)(qt * 64 + w * 16 + 4 * g + r);
    float* op = O + base + rowg * D + c;
#pragma unroll
    for (int nb = 0; nb < 4; ++nb) op[nb * 16] = o_acc[nb][r] * f;
  }
}

extern "C" void kernel_launch(void* const* d_in, const int* in_sizes, int n_in,
                              void* d_out, int out_size, void* d_ws, size_t ws_size,
                              hipStream_t stream) {
  (void)in_sizes; (void)n_in; (void)out_size;
  const float* Q = (const float*)d_in[0];
  const float* K = (const float*)d_in[1];
  const float* V = (const float*)d_in[2];
  float* O = (float*)d_out;
  constexpr size_t NEED = 2ull * 2 * 16 * 2048 * 64 * sizeof(short);  // 16.78 MB
  if (ws_size >= NEED && d_ws) {
    short* Kbf = (short*)d_ws;
    short* VT = Kbf + 2 * 16 * 2048 * 64;
    hipLaunchKernelGGL(conv_kv_kernel, dim3(1024), dim3(256), 0, stream, K, V, Kbf, VT);
    hipLaunchKernelGGL(attn_fwd_v3, dim3(512), dim3(256), 0, stream, Q, Kbf, VT, O);
  } else {
    hipLaunchKernelGGL(attn_fwd_v1, dim3(1024), dim3(256), 0, stream, Q, K, V, O);
  }
}

// Round 7
// 165.056 us; speedup vs baseline: 1.3701x; 1.0271x over previous
//
#include <hip/hip_runtime.h>
#include <hip/hip_bf16.h>
#include <stdint.h>

typedef __attribute__((ext_vector_type(4))) float f32x4;
typedef __attribute__((ext_vector_type(16))) float f32x16;
typedef __attribute__((ext_vector_type(8))) short s16x8;

__device__ __forceinline__ short f2bf(float f) {
    union { float f; uint32_t u; } v; v.f = f;
    uint32_t r = (v.u + 0x7FFFu + ((v.u >> 16) & 1u)) >> 16;
    return (short)(uint16_t)r;
}

__device__ __forceinline__ uint32_t pk2(float a, float b) {
  union { __hip_bfloat162 h; uint32_t u; } v;
  v.h = __float22bfloat162_rn(make_float2(a, b));
  return v.u;
}

__device__ __forceinline__ void async16(const short* g, short* lds) {
  __builtin_amdgcn_global_load_lds(
      (const __attribute__((address_space(1))) uint32_t*)g,
      (__attribute__((address_space(3))) uint32_t*)lds, 16, 0, 0);
}

// ---- fused pre-pass: K fp32->bf16 (same layout) + V fp32 -> permuted V^T ----
// V^T slot order within each 16-kv group: quads [q0 q2 q1 q3] (sigma trick) so
// PV B-fragments (P packed from C-layout regs) need no cross-lane exchange.
__global__ __launch_bounds__(256) void conv_kv_kernel(
    const float* __restrict__ K, const float* __restrict__ V,
    short* __restrict__ Kbf, short* __restrict__ VT) {
  __shared__ short t[64][72];  // padded transpose buffer
  const int bh = blockIdx.x >> 5;
  const int st = blockIdx.x & 31;
  const size_t base = (size_t)bh * 131072;  // 2048*64

  // --- part A: K convert (row-major passthrough) ---
  {
    const int row = threadIdx.x >> 2;
    const int cb = (threadIdx.x & 3) * 16;
    const float* kp = K + base + (size_t)(st * 64 + row) * 64 + cb;
    union { short s[16]; int4 v[2]; } o;
#pragma unroll
    for (int j = 0; j < 16; j += 4) {
      f32x4 a = *(const f32x4*)(kp + j);
#pragma unroll
      for (int q = 0; q < 4; ++q) o.s[j + q] = f2bf(a[q]);
    }
    short* out = Kbf + base + (size_t)(st * 64 + row) * 64 + cb;
    *(int4*)(out) = o.v[0];
    *(int4*)(out + 8) = o.v[1];
  }

  // --- part B: V transpose + quad-permute ---
  {
    const int s_loc = threadIdx.x >> 2;
    const int dch = (threadIdx.x & 3) * 16;
    const float* p = V + base + (size_t)(st * 64 + s_loc) * 64 + dch;
#pragma unroll
    for (int j = 0; j < 16; j += 4) {
      f32x4 a = *(const f32x4*)(p + j);
#pragma unroll
      for (int q = 0; q < 4; ++q) t[s_loc][dch + j + q] = f2bf(a[q]);
    }
  }
  __syncthreads();
  {
    const int d_loc = threadIdx.x >> 2;
    const int sch = (threadIdx.x & 3) * 16;
    union { short s[16]; int4 v[2]; } o;
#pragma unroll
    for (int i = 0; i < 4; ++i) {
      o.s[i]      = t[sch + i][d_loc];
      o.s[4 + i]  = t[sch + 8 + i][d_loc];
      o.s[8 + i]  = t[sch + 4 + i][d_loc];
      o.s[12 + i] = t[sch + 12 + i][d_loc];
    }
    short* out = VT + base + (size_t)d_loc * 2048 + st * 64 + sch;
    *(int4*)(out) = o.v[0];
    *(int4*)(out + 8) = o.v[1];
  }
}

// -------- main kernel v4: swapped-QK^T 32x32 + split-KV warp pairs ----------
// Block: 256 thr. Warp w: qhalf=w&1 (32 q-rows), kvhalf=w>>1 (1024 kv).
// KVBLK=32, double-buffered. End: warp pairs merge (m,l,O) via LDS.
// Grid 1024 -> 4 blocks/CU x 4 waves = 16 waves/CU (vs 8 before).
__global__ __launch_bounds__(256) void attn_fwd_v4(
    const float* __restrict__ Q, const short* __restrict__ Kbf,
    const short* __restrict__ VT, float* __restrict__ O) {
  constexpr int S = 2048, D = 64;
  constexpr int NT = 32;              // 1024 kv per half / 32 per tile
  constexpr float K1 = 0.28853901f;   // SCALE * log2(e)
  constexpr float THR = 11.5415603f;  // 8 nats in log2 units

  __shared__ short lds_s[16384];  // 32KB: K tiles [0,8192), V tiles [8192,16384)

  const int tid = threadIdx.x;
  const int w = tid >> 6;
  const int l = tid & 63;
  const int hi = l >> 5;
  const int c32 = l & 31;
  const int qhalf = w & 1;
  const int kvhalf = w >> 1;

  // XCD-chunked remap (1024 % 8 == 0, bijective): each XCD owns 4 heads.
  const int rid = (blockIdx.x & 7) * 128 + (blockIdx.x >> 3);
  const int bh = rid >> 5;
  const int qt = rid & 31;
  const size_t base = (size_t)bh * (size_t)(S * D);
  const int qrow = qt * 64 + qhalf * 32 + c32;

  const short* Kp = Kbf + base;
  const short* Vp = VT + base;

  // ---- Q fragments (pre-scaled by SCALE*log2e): B-frag for mfma(K,Q) ----
  s16x8 qreg[4];
  {
    const float* qp = Q + base + (size_t)qrow * D;
#pragma unroll
    for (int j = 0; j < 4; ++j) {
      f32x4 a = *(const f32x4*)(qp + j * 16 + hi * 8);
      f32x4 b = *(const f32x4*)(qp + j * 16 + hi * 8 + 4);
      union { uint32_t u[4]; s16x8 v; } pk;
      pk.u[0] = pk2(a[0] * K1, a[1] * K1);
      pk.u[1] = pk2(a[2] * K1, a[3] * K1);
      pk.u[2] = pk2(b[0] * K1, b[1] * K1);
      pk.u[3] = pk2(b[2] * K1, b[3] * K1);
      qreg[j] = pk.v;
    }
  }

  // ---- staging offsets: 1 x 16B chunk per (array, kvhalf) per thread ----
  // K tile: 32 rows x 64 d shorts; LDS chunk t=(r*8+ch) <- K[kv0+r][(ch^(r&7))*8]
  // V tile: LDS row r holds d-pair {2r, 2r+(ch>>2)}; kv-chunk (ch&3)^(r&3).
  const int rS = tid >> 3, chS = tid & 7;
  const int kSrcOff = rS * 64 + ((chS ^ (rS & 7)) << 3);
  const int dV = 2 * rS + (chS >> 2);
  const int vSrcOff = dV * 2048 + (((chS & 3) ^ (rS & 3)) << 3);
  const int ldsOff = tid * 8;  // shorts

  short* kS0 = lds_s;          // [buf][half][2048]
  short* vS0 = lds_s + 8192;

#define STAGE(buf, kt)                                                    \
  do {                                                                    \
    _Pragma("unroll") for (int h = 0; h < 2; ++h) {                       \
      const int kv0 = h * 1024 + (kt) * 32;                               \
      async16(Kp + kv0 * 64 + kSrcOff, kS0 + ((buf)*2 + h) * 2048 + ldsOff); \
      async16(Vp + kv0 + vSrcOff, vS0 + ((buf)*2 + h) * 2048 + ldsOff);   \
    }                                                                     \
  } while (0)

  f32x16 o0, o1;
#pragma unroll
  for (int i = 0; i < 16; ++i) { o0[i] = 0.f; o1[i] = 0.f; }
  float m = -1e30f, lsum = 0.f;

  int cur = 0;
  STAGE(0, 0);
  for (int kt = 0; kt < NT; ++kt) {
    __syncthreads();  // compiler drains vmcnt before barrier: buf[cur] ready
    if (kt + 1 < NT) STAGE(cur ^ 1, kt + 1);
    const char* kB = (const char*)(kS0 + (cur * 2 + kvhalf) * 2048);
    const char* vB = (const char*)(vS0 + (cur * 2 + kvhalf) * 2048);

    // ---- scores: S^T[kv 32][q 32] = K * Q^T ----
    f32x16 s;
#pragma unroll
    for (int i = 0; i < 16; ++i) s[i] = 0.f;
    const int ksw = (c32 & 7) << 4;
    __builtin_amdgcn_s_setprio(1);
#pragma unroll
    for (int j = 0; j < 4; ++j) {
      s16x8 a = *(const s16x8*)(kB + c32 * 128 + ((j * 32 + hi * 16) ^ ksw));
      s = __builtin_amdgcn_mfma_f32_32x32x16_bf16(a, qreg[j], s, 0, 0, 0);
    }
    __builtin_amdgcn_s_setprio(0);

    // ---- online softmax (base-2; q = c32 per lane) ----
    float t8[8];
#pragma unroll
    for (int i = 0; i < 8; ++i) t8[i] = fmaxf(s[2 * i], s[2 * i + 1]);
    float t4a = fmaxf(fmaxf(t8[0], t8[1]), fmaxf(t8[2], t8[3]));
    float t4b = fmaxf(fmaxf(t8[4], t8[5]), fmaxf(t8[6], t8[7]));
    float tm = fmaxf(t4a, t4b);
    tm = fmaxf(tm, __shfl_xor(tm, 32));
    if (!__all(tm <= m + THR)) {  // defer-max (T13)
      const float mn = fmaxf(m, tm);
      const float scl = exp2f(m - mn);
      lsum *= scl;
      o0 *= scl;
      o1 *= scl;
      m = mn;
    }
    float p[16];
#pragma unroll
    for (int i = 0; i < 16; ++i) p[i] = exp2f(s[i] - m);
    float s8[8];
#pragma unroll
    for (int i = 0; i < 8; ++i) s8[i] = p[2 * i] + p[2 * i + 1];
    float rs = ((s8[0] + s8[1]) + (s8[2] + s8[3])) +
               ((s8[4] + s8[5]) + (s8[6] + s8[7]));
    rs += __shfl_xor(rs, 32);
    lsum += rs;

    // ---- pack P (register-only; sigma order matches VT workspace) ----
    union { uint32_t u[8]; s16x8 v[2]; } wp;
#pragma unroll
    for (int i = 0; i < 8; ++i) wp.u[i] = pk2(p[2 * i], p[2 * i + 1]);

    // ---- O^T += V^T * P ----
    __builtin_amdgcn_s_setprio(1);
#pragma unroll
    for (int c = 0; c < 2; ++c) {
      const s16x8 bp = wp.v[c];
      {
        const int d = c32;  // o0
        const int r = d >> 1;
        s16x8 av = *(const s16x8*)(vB + r * 128 + (d & 1) * 64 +
                                   (((c * 2 + hi) ^ (r & 3)) << 4));
        o0 = __builtin_amdgcn_mfma_f32_32x32x16_bf16(av, bp, o0, 0, 0, 0);
      }
      {
        const int d = 32 + c32;  // o1
        const int r = d >> 1;
        s16x8 av = *(const s16x8*)(vB + r * 128 + (d & 1) * 64 +
                                   (((c * 2 + hi) ^ (r & 3)) << 4));
        o1 = __builtin_amdgcn_mfma_f32_32x32x16_bf16(av, bp, o1, 0, 0, 0);
      }
    }
    __builtin_amdgcn_s_setprio(0);
    cur ^= 1;
  }
#undef STAGE

  // ---- combine warp pairs (kvhalf 1 -> LDS; kvhalf 0 merges + stores) ----
  __syncthreads();  // all LDS tile traffic done
  float* comb = (float*)lds_s;  // [qhalf*64 + l][36]: m, l, o0[16], o1[16]
  if (kvhalf == 1) {
    float* dst = comb + (qhalf * 64 + l) * 36;
    dst[0] = m;
    dst[1] = lsum;
#pragma unroll
    for (int i = 0; i < 16; ++i) { dst[2 + i] = o0[i]; dst[18 + i] = o1[i]; }
  }
  __syncthreads();
  if (kvhalf == 0) {
    const float* src = comb + (qhalf * 64 + l) * 36;
    const float mb = src[0], lb = src[1];
    const float mm = fmaxf(m, mb);
    const float a = exp2f(m - mm);
    const float b = exp2f(mb - mm);
    const float f = 2.0f / (lsum * a + lb * b);
    float* op = O + base + (size_t)qrow * D;
#pragma unroll
    for (int rq = 0; rq < 4; ++rq) {
      const int d0 = rq * 8 + 4 * hi;
      f32x4 v0, v1;
#pragma unroll
      for (int i = 0; i < 4; ++i) {
        v0[i] = (o0[rq * 4 + i] * a + src[2 + rq * 4 + i] * b) * f;
        v1[i] = (o1[rq * 4 + i] * a + src[18 + rq * 4 + i] * b) * f;
      }
      *(f32x4*)(op + d0) = v0;
      *(f32x4*)(op + d0 + 32) = v1;
    }
  }
}

// ================= fallback (round-0 kernel, no workspace) ===================
__global__ __launch_bounds__(256) void attn_fwd_v1(
    const float* __restrict__ Q, const float* __restrict__ K,
    const float* __restrict__ V, float* __restrict__ O) {
  constexpr int S = 2048, D = 64;
  constexpr float SCALE = 0.2f, FACTOR = 2.0f;
  constexpr int KVBLK = 64, NT = S / KVBLK;
  __shared__ short kT[64 * 64];
  __shared__ short vT[64 * 64];
  __shared__ short pT[4][16 * 64];
  const int tid = threadIdx.x;
  const int w = tid >> 6, l = tid & 63, g = l >> 4, c = l & 15;
  const int bh = blockIdx.x >> 5, qt = blockIdx.x & 31;
  const size_t base = (size_t)bh * (size_t)(S * D);
  char* kB = (char*)kT; char* vB = (char*)vT; char* pB = (char*)pT[w];
  s16x8 qa[2];
  {
    const float* qp = Q + base + (size_t)(qt * 64 + w * 16 + c) * D + g * 8;
#pragma unroll
    for (int kk = 0; kk < 2; ++kk) {
      f32x4 q0 = *(const f32x4*)(qp + kk * 32);
      f32x4 q1 = *(const f32x4*)(qp + kk * 32 + 4);
      s16x8 a;
#pragma unroll
      for (int i = 0; i < 4; ++i) { a[i] = f2bf(q0[i]); a[4 + i] = f2bf(q1[i]); }
      qa[kk] = a;
    }
  }
  f32x4 o_acc[4];
#pragma unroll
  for (int nb = 0; nb < 4; ++nb) o_acc[nb] = (f32x4){0.f, 0.f, 0.f, 0.f};
  float m_r[4], l_r[4];
#pragma unroll
  for (int r = 0; r < 4; ++r) { m_r[r] = -1e30f; l_r[r] = 0.f; }
  const int krow = tid >> 2, kcb = tid & 3;
  const int vpr = (tid >> 3) * 2, vpc = (tid & 7) * 8;
  for (int kt = 0; kt < NT; ++kt) {
    const int kv0 = kt * KVBLK;
    __syncthreads();
    {
      const float* kp = K + base + (size_t)(kv0 + krow) * D + kcb * 16;
      f32x4 a0 = *(const f32x4*)(kp);
      f32x4 a1 = *(const f32x4*)(kp + 4);
      f32x4 a2 = *(const f32x4*)(kp + 8);
      f32x4 a3 = *(const f32x4*)(kp + 12);
      union { short s[8]; int4 v; } p0, p1;
#pragma unroll
      for (int i = 0; i < 4; ++i) {
        p0.s[i] = f2bf(a0[i]); p0.s[4 + i] = f2bf(a1[i]);
        p1.s[i] = f2bf(a2[i]); p1.s[4 + i] = f2bf(a3[i]);
      }
      const int sw = (krow & 7) << 4;
      *(int4*)(kB + krow * 128 + ((kcb * 32) ^ sw)) = p0.v;
      *(int4*)(kB + krow * 128 + ((kcb * 32 + 16) ^ sw)) = p1.v;
    }
    {
      const float* vp = V + base + (size_t)(kv0 + vpr) * D + vpc;
      f32x4 r0a = *(const f32x4*)(vp);
      f32x4 r0b = *(const f32x4*)(vp + 4);
      f32x4 r1a = *(const f32x4*)(vp + D);
      f32x4 r1b = *(const f32x4*)(vp + D + 4);
      float lo[8] = {r0a[0], r0a[1], r0a[2], r0a[3], r0b[0], r0b[1], r0b[2], r0b[3]};
      float hi2[8] = {r1a[0], r1a[1], r1a[2], r1a[3], r1b[0], r1b[1], r1b[2], r1b[3]};
#pragma unroll
      for (int i = 0; i < 8; ++i) {
        uint32_t pk = (uint32_t)(uint16_t)f2bf(lo[i]) |
                      ((uint32_t)(uint16_t)f2bf(hi2[i]) << 16);
        const int col = vpc + i;
        *(uint32_t*)(vB + col * 128 + ((vpr * 2) ^ ((col & 7) << 4))) = pk;
      }
    }
    __syncthreads();
    f32x4 sc[4];
#pragma unroll
    for (int nb = 0; nb < 4; ++nb) sc[nb] = (f32x4){0.f, 0.f, 0.f, 0.f};
#pragma unroll
    for (int kk = 0; kk < 2; ++kk) {
#pragma unroll
      for (int nb = 0; nb < 4; ++nb) {
        const int row = nb * 16 + c;
        s16x8 b = *(const s16x8*)(kB + row * 128 +
                                  ((kk * 64 + g * 16) ^ ((row & 7) << 4)));
        sc[nb] = __builtin_amdgcn_mfma_f32_16x16x32_bf16(qa[kk], b, sc[nb], 0, 0, 0);
      }
    }
    float p[4][4]; float esc[4];
#pragma unroll
    for (int r = 0; r < 4; ++r) {
      float mx = fmaxf(fmaxf(sc[0][r], sc[1][r]), fmaxf(sc[2][r], sc[3][r]));
#pragma unroll
      for (int mask = 1; mask < 16; mask <<= 1)
        mx = fmaxf(mx, __shfl_xor(mx, mask, 64));
      mx *= SCALE;
      const float mnew = fmaxf(m_r[r], mx);
      esc[r] = __expf(m_r[r] - mnew);
      float rs = 0.f;
#pragma unroll
      for (int nb = 0; nb < 4; ++nb) {
        float e = __expf(sc[nb][r] * SCALE - mnew);
        p[nb][r] = e; rs += e;
      }
#pragma unroll
      for (int mask = 1; mask < 16; mask <<= 1)
        rs += __shfl_xor(rs, mask, 64);
      l_r[r] = l_r[r] * esc[r] + rs;
      m_r[r] = mnew;
    }
#pragma unroll
    for (int nb = 0; nb < 4; ++nb)
#pragma unroll
      for (int r = 0; r < 4; ++r) o_acc[nb][r] *= esc[r];
#pragma unroll
    for (int nb = 0; nb < 4; ++nb) {
#pragma unroll
      for (int r = 0; r < 4; ++r) {
        const int row = 4 * g + r;
        const int colb = (nb * 16 + c) * 2;
        *(short*)(pB + row * 128 + (colb ^ ((row & 7) << 4))) = f2bf(p[nb][r]);
      }
    }
    asm volatile("s_waitcnt lgkmcnt(0)" ::: "memory");
#pragma unroll
    for (int kk = 0; kk < 2; ++kk) {
      s16x8 pa = *(const s16x8*)(pB + c * 128 +
                                 ((kk * 64 + g * 16) ^ ((c & 7) << 4)));
#pragma unroll
      for (int nb = 0; nb < 4; ++nb) {
        const int row = nb * 16 + c;
        s16x8 vb = *(const s16x8*)(vB + row * 128 +
                                   ((kk * 64 + g * 16) ^ ((row & 7) << 4)));
        o_acc[nb] = __builtin_amdgcn_mfma_f32_16x16x32_bf16(pa, vb, o_acc[nb], 0, 0, 0);
      }
    }
  }
#pragma unroll
  for (int r = 0; r < 4; ++r) {
    const float f = FACTOR / l_r[r];
    const size_t rowg = (size_t)(qt * 64 + w * 16 + 4 * g + r);
    float* op = O + base + rowg * D + c;
#pragma unroll
    for (int nb = 0; nb < 4; ++nb) op[nb * 16] = o_acc[nb][r] * f;
  }
}

extern "C" void kernel_launch(void* const* d_in, const int* in_sizes, int n_in,
                              void* d_out, int out_size, void* d_ws, size_t ws_size,
                              hipStream_t stream) {
  (void)in_sizes; (void)n_in; (void)out_size;
  const float* Q = (const float*)d_in[0];
  const float* K = (const float*)d_in[1];
  const float* V = (const float*)d_in[2];
  float* O = (float*)d_out;
  constexpr size_t NEED = 2ull * 2 * 16 * 2048 * 64 * sizeof(short);  // 16.78 MB
  if (ws_size >= NEED && d_ws) {
    short* Kbf = (short*)d_ws;
    short* VT = Kbf + 2 * 16 * 2048 * 64;
    hipLaunchKernelGGL(conv_kv_kernel, dim3(1024), dim3(256), 0, stream, K, V, Kbf, VT);
    hipLaunchKernelGGL(attn_fwd_v4, dim3(1024), dim3(256), 0, stream, Q, Kbf, VT, O);
  } else {
    hipLaunchKernelGGL(attn_fwd_v1, dim3(1024), dim3(256), 0, stream, Q, K, V, O);
  }
}